// Round 2
// baseline (397.050 us; speedup 1.0000x reference)
//
#include <hip/hip_runtime.h>

// MultiCenterLoss: loss = sum_{label==0} min_c ||f - c + eps||_2 / (count + 1e-5)
// ||f-c+eps||^2 = [f2 + 2*eps*fs + eps^2*D] + [c2 - 2*eps*cs] - 2*f.c
// min over c commutes with the per-sample constant, so k_dist only needs
// min_c (cc[c] - 2*f.c); the per-sample constant is added in k_final_out.

constexpr int N = 16384;
constexpr int D = 1024;
constexpr int C = 1024;
constexpr float EPS = 1e-6f;

constexpr int SB = 16;        // samples per block
constexpr int CB = 128;       // centers per block
constexpr int DS = 32;        // d per stage
constexpr int NS = D / DS;    // 32 stages
constexpr int PITCH = 36;     // LDS row pitch in floats (16B-aligned rows, spreads banks)
constexpr int NSPLIT = C / CB;  // 8 center splits

// order-preserving float<->uint map (finite floats)
__device__ inline unsigned mapf(float f) {
  unsigned b = __float_as_uint(f);
  return (b & 0x80000000u) ? ~b : (b | 0x80000000u);
}
__device__ inline float unmapf(unsigned u) {
  return __uint_as_float((u & 0x80000000u) ? (u ^ 0x80000000u) : ~u);
}

// fused setup: minmapped init + label==0 gather + per-center constant
// cc[c] = sum(c^2) - 2*eps*sum(c).  grid 64 x 256.
__global__ __launch_bounds__(256) void k_setup(const float* __restrict__ cent,
                                               const int* __restrict__ labels,
                                               unsigned* __restrict__ count,
                                               unsigned* __restrict__ sel,
                                               unsigned* __restrict__ minmapped,
                                               float* __restrict__ cc) {
  int b = blockIdx.x, t = threadIdx.x;
  int n = b * 256 + t;
  minmapped[n] = 0xFFFFFFFFu;
  if (labels[n] == 0) {
    unsigned slot = atomicAdd(count, 1u);
    sel[slot] = (unsigned)n;
  }
  int w = t >> 6, lane = t & 63;
#pragma unroll
  for (int e = 0; e < 4; ++e) {
    int c = b * 16 + w * 4 + e;
    const float* row = cent + (size_t)c * D;
    float s1 = 0.f, s2 = 0.f;
#pragma unroll
    for (int j = 0; j < D / 64; ++j) {
      float v = row[lane + 64 * j];
      s1 += v;
      s2 += v * v;
    }
#pragma unroll
    for (int off = 32; off; off >>= 1) {
      s1 += __shfl_down(s1, off);
      s2 += __shfl_down(s2, off);
    }
    if (lane == 0) cc[c] = s2 - 2.0f * EPS * s1;
  }
}

// block: 16 samples x 128 centers. 4 waves split D (8 d each per 32-d stage).
// per lane: acc[8][4] -> sample s = 8*ty + i, center c = tx + 32*k.
// Row-major LDS tiles (pitch 36), register-staged prefetch of next stage.
__global__ __launch_bounds__(256, 4) void k_dist(const float* __restrict__ feat,
                                                 const float* __restrict__ cent,
                                                 const float* __restrict__ cc,
                                                 const unsigned* __restrict__ count,
                                                 const unsigned* __restrict__ sel,
                                                 unsigned* __restrict__ minmapped) {
  __shared__ float Ct[CB][PITCH];  // 18.0 KB
  __shared__ float Ft[SB][PITCH];  // 2.3 KB
  __shared__ unsigned rows[SB];

  unsigned cnt = *count;
  unsigned sbase = blockIdx.x * SB;
  if (sbase >= cnt) return;  // static worst-case grid; inactive blocks exit
  unsigned cbase = blockIdx.y * CB;

  int tid = threadIdx.x;
  int lane = tid & 63, w = tid >> 6;
  int tx = lane & 31, ty = lane >> 5;

  if (tid < SB) rows[tid] = sel[min(sbase + (unsigned)tid, cnt - 1u)];
  __syncthreads();

  // staging geometry: C tile = 128 rows x 32 d = 1024 float4, 4 per thread
  //                   F tile = 16 rows x 32 d = 128 float4, threads 0..127
  int cr = tid >> 3;           // C base row; also rows cr+32, cr+64, cr+96
  int ca = (tid & 7) * 4;      // d offset within stage
  const float* cgp = cent + (size_t)(cbase + cr) * D + ca;
  const float* fgp = (tid < 128) ? feat + (size_t)rows[tid >> 3] * D + ca : feat;

  float4 cpre[4];
  float4 fpre;
  auto issue = [&](int d0) {
#pragma unroll
    for (int u = 0; u < 4; ++u)
      cpre[u] = *(const float4*)(cgp + (size_t)32 * u * D + d0);
    if (tid < 128) fpre = *(const float4*)(fgp + d0);
  };
  auto commit = [&]() {
#pragma unroll
    for (int u = 0; u < 4; ++u)
      *(float4*)&Ct[cr + 32 * u][ca] = cpre[u];
    if (tid < 128) *(float4*)&Ft[tid >> 3][ca] = fpre;
  };

  float acc[8][4] = {};

  issue(0);
  commit();
  __syncthreads();

  for (int s = 0; s < NS; ++s) {
    if (s + 1 < NS) issue(DS * (s + 1));  // prefetch hides under compute

    // wave w computes its 8 d-rows: j = 8w + 4q + t4
#pragma unroll
    for (int q = 0; q < 2; ++q) {
      int jb = 8 * w + 4 * q;
      float cv[4][4];
#pragma unroll
      for (int k = 0; k < 4; ++k) {
        float4 v = *(const float4*)&Ct[tx + 32 * k][jb];
        cv[k][0] = v.x; cv[k][1] = v.y; cv[k][2] = v.z; cv[k][3] = v.w;
      }
#pragma unroll
      for (int h = 0; h < 2; ++h) {  // i in two halves to cap VGPR
        float fv[4][4];
#pragma unroll
        for (int i = 0; i < 4; ++i) {
          float4 v = *(const float4*)&Ft[8 * ty + 4 * h + i][jb];
          fv[i][0] = v.x; fv[i][1] = v.y; fv[i][2] = v.z; fv[i][3] = v.w;
        }
#pragma unroll
        for (int t4 = 0; t4 < 4; ++t4)
#pragma unroll
          for (int i = 0; i < 4; ++i)
#pragma unroll
            for (int k = 0; k < 4; ++k)
              acc[4 * h + i][k] = fmaf(fv[i][t4], cv[k][t4], acc[4 * h + i][k]);
      }
    }
    __syncthreads();
    if (s + 1 < NS) commit();
    __syncthreads();
  }

  // cross-wave sum of D-split partials (pitch 33 -> conflict-free), into wave 0
  float* red = &Ct[0][0];  // 4608 floats available, need <= 4223
  if (w >= 2) {
    float* p = red + (size_t)((w - 2) * 64 + lane) * 33;
#pragma unroll
    for (int i = 0; i < 8; ++i)
#pragma unroll
      for (int k = 0; k < 4; ++k) p[i * 4 + k] = acc[i][k];
  }
  __syncthreads();
  if (w < 2) {
    const float* p = red + (size_t)(w * 64 + lane) * 33;
#pragma unroll
    for (int i = 0; i < 8; ++i)
#pragma unroll
      for (int k = 0; k < 4; ++k) acc[i][k] += p[i * 4 + k];
  }
  __syncthreads();
  if (w == 1) {
    float* p = red + (size_t)lane * 33;
#pragma unroll
    for (int i = 0; i < 8; ++i)
#pragma unroll
      for (int k = 0; k < 4; ++k) p[i * 4 + k] = acc[i][k];
  }
  __syncthreads();
  if (w == 0) {
    const float* p = red + (size_t)lane * 33;
#pragma unroll
    for (int i = 0; i < 8; ++i)
#pragma unroll
      for (int k = 0; k < 4; ++k) acc[i][k] += p[i * 4 + k];

    float ccv[4];
#pragma unroll
    for (int k = 0; k < 4; ++k) ccv[k] = cc[cbase + tx + 32 * k];

#pragma unroll
    for (int i = 0; i < 8; ++i) {
      float b0 = 3.4e38f;
#pragma unroll
      for (int k = 0; k < 4; ++k) b0 = fminf(b0, ccv[k] - 2.0f * acc[i][k]);
#pragma unroll
      for (int off = 1; off < 32; off <<= 1) b0 = fminf(b0, __shfl_xor(b0, off));
      if (tx == 0) {
        unsigned sidx = sbase + (unsigned)(8 * ty + i);
        if (sidx < cnt) atomicMin(&minmapped[sidx], mapf(b0));
      }
    }
  }
}

// per selected sample: ff = sum(f^2) + 2*eps*sum(f) + eps^2*D; combine + sum;
// last finishing block writes the final scalar (completion counter).
__global__ __launch_bounds__(256) void k_final_out(const float* __restrict__ feat,
                                                   const unsigned* __restrict__ count,
                                                   const unsigned* __restrict__ sel,
                                                   const unsigned* __restrict__ minmapped,
                                                   float* __restrict__ num,
                                                   unsigned* __restrict__ done,
                                                   float* __restrict__ out) {
  unsigned cnt = *count;
  unsigned w = blockIdx.x * 4 + (threadIdx.x >> 6);
  int lane = threadIdx.x & 63;
  unsigned stride = gridDim.x * 4;
  for (unsigned slot = w; slot < cnt; slot += stride) {
    const float* row = feat + (size_t)sel[slot] * D;
    float s1 = 0.f, s2 = 0.f;
#pragma unroll
    for (int j = 0; j < D / 64; ++j) {
      float v = row[lane + 64 * j];
      s1 += v;
      s2 += v * v;
    }
#pragma unroll
    for (int off = 32; off; off >>= 1) {
      s1 += __shfl_down(s1, off);
      s2 += __shfl_down(s2, off);
    }
    if (lane == 0) {
      float ff = s2 + 2.0f * EPS * s1 + EPS * EPS * (float)D;
      float sq = ff + unmapf(minmapped[slot]);
      atomicAdd(num, sqrtf(fmaxf(sq, 0.0f)));
    }
  }
  __syncthreads();
  if (threadIdx.x == 0) {
    __threadfence();
    unsigned v = atomicAdd(done, 1u);
    if (v == gridDim.x - 1) {
      float total = atomicAdd(num, 0.0f);  // coherent read
      out[0] = total / ((float)cnt + 1e-5f);
    }
  }
}

extern "C" void kernel_launch(void* const* d_in, const int* in_sizes, int n_in,
                              void* d_out, int out_size, void* d_ws, size_t ws_size,
                              hipStream_t stream) {
  const float* feat = (const float*)d_in[0];
  const int* labels = (const int*)d_in[1];
  const float* cent = (const float*)d_in[2];
  float* out = (float*)d_out;

  unsigned* count = (unsigned*)d_ws;                                // @0
  float* num = (float*)((char*)d_ws + 4);                           // @4
  unsigned* done = (unsigned*)((char*)d_ws + 8);                    // @8
  unsigned* minmapped = (unsigned*)((char*)d_ws + 16);              // N u32
  unsigned* sel = (unsigned*)((char*)d_ws + 16 + 4 * (size_t)N);    // N u32
  float* cc = (float*)((char*)d_ws + 16 + 8 * (size_t)N);           // C f32

  hipMemsetAsync(d_ws, 0, 16, stream);
  k_setup<<<64, 256, 0, stream>>>(cent, labels, count, sel, minmapped, cc);

  dim3 gd(N / SB, NSPLIT);  // worst-case 1024 x 8; inactive blocks exit
  k_dist<<<gd, 256, 0, stream>>>(feat, cent, cc, count, sel, minmapped);

  k_final_out<<<128, 256, 0, stream>>>(feat, count, sel, minmapped, num, done, out);
}

// Round 3
// 154.761 us; speedup vs baseline: 2.5656x; 2.5656x over previous
//
#include <hip/hip_runtime.h>

// MultiCenterLoss: loss = sum_{label==0} min_c ||f - c + eps||_2 / (count + 1e-5)
// ||f-c+eps||^2 = [f2 + 2*eps*fs + eps^2*D] + [c2 - 2*eps*cs] - 2*f.c
// min over c commutes with the per-sample constant, so k_dist only needs
// min_c (cc[c] - 2*f.c); the per-sample constant is added in k_final_out.
// f.c computed with bf16 MFMA (16x16x32); |loss error| << 0.85 threshold.

constexpr int N = 16384;
constexpr int D = 1024;
constexpr int C = 1024;
constexpr float EPS = 1e-6f;

constexpr int SB = 16;    // samples per block
constexpr int CB = 128;   // centers per block
constexpr int BK = 64;    // K elements per stage
constexpr int NSPLIT = C / CB;

typedef __attribute__((ext_vector_type(8))) short bf16x8;
typedef __attribute__((ext_vector_type(4))) float f32x4;

// order-preserving float<->uint map (finite floats)
__device__ inline unsigned mapf(float f) {
  unsigned b = __float_as_uint(f);
  return (b & 0x80000000u) ? ~b : (b | 0x80000000u);
}
__device__ inline float unmapf(unsigned u) {
  return __uint_as_float((u & 0x80000000u) ? (u ^ 0x80000000u) : ~u);
}

// fp32 -> bf16 bits, round-to-nearest-even (inputs are finite)
__device__ inline unsigned short f2bf(float x) {
  unsigned u = __float_as_uint(x);
  return (unsigned short)((u + 0x7FFFu + ((u >> 16) & 1u)) >> 16);
}

#define GLOAD_LDS16(gp, lp)                                        \
  __builtin_amdgcn_global_load_lds(                                \
      (const __attribute__((address_space(1))) void*)(gp),         \
      (__attribute__((address_space(3))) void*)(lp), 16, 0, 0)

// fused setup: minmapped init + label==0 gather + cc[c] = sum(c^2)-2*eps*sum(c)
// + centers fp32 -> bf16 (linear row-major).  grid 64 x 256.
__global__ __launch_bounds__(256) void k_setup(const float* __restrict__ cent,
                                               const int* __restrict__ labels,
                                               unsigned* __restrict__ count,
                                               unsigned* __restrict__ sel,
                                               unsigned* __restrict__ minmapped,
                                               float* __restrict__ cc,
                                               unsigned short* __restrict__ cent_bf) {
  int b = blockIdx.x, t = threadIdx.x;
  int n = b * 256 + t;
  minmapped[n] = 0xFFFFFFFFu;
  if (labels[n] == 0) {
    unsigned slot = atomicAdd(count, 1u);
    sel[slot] = (unsigned)n;
  }
  // bf16 conversion of this block's 16 center rows
  size_t base = (size_t)b * 16 * D;
#pragma unroll
  for (int u = 0; u < 16; ++u) {
    size_t off = base + (size_t)(u * 256 + t) * 4;
    float4 v = *(const float4*)(cent + off);
    short4 s4 = make_short4((short)f2bf(v.x), (short)f2bf(v.y),
                            (short)f2bf(v.z), (short)f2bf(v.w));
    *(short4*)(cent_bf + off) = s4;
  }
  // per-center constant (fp32, rows are L1/L2 hot now)
  int w = t >> 6, lane = t & 63;
#pragma unroll
  for (int e = 0; e < 4; ++e) {
    int c = b * 16 + w * 4 + e;
    const float* row = cent + (size_t)c * D;
    float s1 = 0.f, s2 = 0.f;
#pragma unroll
    for (int j = 0; j < D / 64; ++j) {
      float v = row[lane + 64 * j];
      s1 += v;
      s2 += v * v;
    }
#pragma unroll
    for (int off = 32; off; off >>= 1) {
      s1 += __shfl_down(s1, off);
      s2 += __shfl_down(s2, off);
    }
    if (lane == 0) cc[c] = s2 - 2.0f * EPS * s1;
  }
}

// 16 samples x 128 centers per block, 4 waves (wave w owns centers [32w,32w+32)).
// Tiles [rows][64] bf16 in LDS with 16B-chunk XOR swizzle (j ^= row&7):
// C-tile via global_load_lds (linear dest, inverse-swizzled per-lane SOURCE),
// F-tile reg-staged fp32 -> bf16 -> swizzled ds_write.
__global__ __launch_bounds__(256) void k_dist(const float* __restrict__ feat,
                                              const unsigned short* __restrict__ cent_bf,
                                              const float* __restrict__ cc,
                                              const unsigned* __restrict__ count,
                                              const unsigned* __restrict__ sel,
                                              unsigned* __restrict__ minmapped) {
  __shared__ __align__(16) unsigned short Cb[CB * BK];  // 16 KB
  __shared__ __align__(16) unsigned short Fb[SB * BK];  // 2 KB
  __shared__ unsigned rows[SB];

  unsigned cnt = *count;
  unsigned sbase = blockIdx.x * SB;
  if (sbase >= cnt) return;  // static worst-case grid; inactive blocks exit
  unsigned cbase = blockIdx.y * CB;

  int tid = threadIdx.x;
  int lane = tid & 63, w = tid >> 6;

  if (tid < SB) rows[tid] = sel[min(sbase + (unsigned)tid, cnt - 1u)];
  __syncthreads();

  // F staging geometry: thread t -> sample s = t>>4, k4 = (t&15)*4
  int fs = tid >> 4;
  int fk4 = (tid & 15) * 4;
  const float* fsrc = feat + (size_t)rows[fs] * D + fk4;
  int fj = fk4 >> 3, fhalf = (fk4 >> 2) & 1;
  int foff = fs * BK + ((fj ^ (fs & 7)) << 3) + (fhalf << 2);

  f32x4 acc0 = {0.f, 0.f, 0.f, 0.f}, acc1 = {0.f, 0.f, 0.f, 0.f};
  int arow = lane & 15, kg = lane >> 4;
  int c0 = w * 32 + (lane & 15), c1 = c0 + 16;

  for (int t = 0; t < D / BK; ++t) {
    int kbase = t * BK;
    // stage C: 1024 16B chunks, 4 per thread, swizzled source
#pragma unroll
    for (int u = 0; u < 4; ++u) {
      int chunk = (w * 4 + u) * 64 + lane;
      int r = chunk >> 3, j = chunk & 7;
      int jsrc = j ^ (r & 7);
      const unsigned short* src =
          cent_bf + (size_t)(cbase + r) * D + kbase + jsrc * 8;
      GLOAD_LDS16(src, &Cb[chunk * 8]);
    }
    // stage F: one float4 per thread, convert, swizzled ds_write
    {
      float4 v = *(const float4*)(fsrc + kbase);
      *(short4*)&Fb[foff] = make_short4((short)f2bf(v.x), (short)f2bf(v.y),
                                        (short)f2bf(v.z), (short)f2bf(v.w));
    }
    __syncthreads();

#pragma unroll
    for (int ks = 0; ks < 2; ++ks) {
      int jj = (ks << 2) + kg;
      bf16x8 a = *(const bf16x8*)&Fb[arow * BK + ((jj ^ (arow & 7)) << 3)];
      bf16x8 b0 = *(const bf16x8*)&Cb[c0 * BK + ((jj ^ (c0 & 7)) << 3)];
      bf16x8 b1 = *(const bf16x8*)&Cb[c1 * BK + ((jj ^ (c1 & 7)) << 3)];
      acc0 = __builtin_amdgcn_mfma_f32_16x16x32_bf16(a, b0, acc0, 0, 0, 0);
      acc1 = __builtin_amdgcn_mfma_f32_16x16x32_bf16(a, b1, acc1, 0, 0, 0);
    }
    __syncthreads();
  }

  // epilogue: cand = cc[c] - 2*dot; D-layout: col=lane&15, row=(lane>>4)*4+reg
  float ccv0 = cc[cbase + c0];
  float ccv1 = cc[cbase + c1];
#pragma unroll
  for (int reg = 0; reg < 4; ++reg) {
    float v = fminf(ccv0 - 2.0f * acc0[reg], ccv1 - 2.0f * acc1[reg]);
#pragma unroll
    for (int off = 1; off < 16; off <<= 1) v = fminf(v, __shfl_xor(v, off));
    if ((lane & 15) == 0) {
      unsigned sidx = sbase + (unsigned)((lane >> 4) * 4 + reg);
      if (sidx < cnt) atomicMin(&minmapped[sidx], mapf(v));
    }
  }
}

// per selected sample: ff = sum(f^2) + 2*eps*sum(f) + eps^2*D; combine + sum;
// last finishing block writes the final scalar (completion counter).
__global__ __launch_bounds__(256) void k_final_out(const float* __restrict__ feat,
                                                   const unsigned* __restrict__ count,
                                                   const unsigned* __restrict__ sel,
                                                   const unsigned* __restrict__ minmapped,
                                                   float* __restrict__ num,
                                                   unsigned* __restrict__ done,
                                                   float* __restrict__ out) {
  unsigned cnt = *count;
  unsigned w = blockIdx.x * 4 + (threadIdx.x >> 6);
  int lane = threadIdx.x & 63;
  unsigned stride = gridDim.x * 4;
  for (unsigned slot = w; slot < cnt; slot += stride) {
    const float* row = feat + (size_t)sel[slot] * D;
    float s1 = 0.f, s2 = 0.f;
#pragma unroll
    for (int j = 0; j < D / 64; ++j) {
      float v = row[lane + 64 * j];
      s1 += v;
      s2 += v * v;
    }
#pragma unroll
    for (int off = 32; off; off >>= 1) {
      s1 += __shfl_down(s1, off);
      s2 += __shfl_down(s2, off);
    }
    if (lane == 0) {
      float ff = s2 + 2.0f * EPS * s1 + EPS * EPS * (float)D;
      float sq = ff + unmapf(minmapped[slot]);
      atomicAdd(num, sqrtf(fmaxf(sq, 0.0f)));
    }
  }
  __syncthreads();
  if (threadIdx.x == 0) {
    __threadfence();
    unsigned v = atomicAdd(done, 1u);
    if (v == gridDim.x - 1) {
      float total = atomicAdd(num, 0.0f);  // coherent read
      out[0] = total / ((float)cnt + 1e-5f);
    }
  }
}

extern "C" void kernel_launch(void* const* d_in, const int* in_sizes, int n_in,
                              void* d_out, int out_size, void* d_ws, size_t ws_size,
                              hipStream_t stream) {
  const float* feat = (const float*)d_in[0];
  const int* labels = (const int*)d_in[1];
  const float* cent = (const float*)d_in[2];
  float* out = (float*)d_out;

  char* ws = (char*)d_ws;
  unsigned* count = (unsigned*)ws;                         // @0
  float* num = (float*)(ws + 4);                           // @4
  unsigned* done = (unsigned*)(ws + 8);                    // @8
  unsigned* minmapped = (unsigned*)(ws + 16);              // N u32
  unsigned* sel = (unsigned*)(ws + 16 + 4 * (size_t)N);    // N u32
  float* cc = (float*)(ws + 16 + 8 * (size_t)N);           // C f32
  unsigned short* cent_bf =
      (unsigned short*)(ws + 16 + 8 * (size_t)N + 4 * (size_t)C);  // C*D bf16

  hipMemsetAsync(d_ws, 0, 16, stream);
  k_setup<<<64, 256, 0, stream>>>(cent, labels, count, sel, minmapped, cc,
                                  cent_bf);

  dim3 gd(N / SB, NSPLIT);  // worst-case 1024 x 8; inactive blocks exit fast
  k_dist<<<gd, 256, 0, stream>>>(feat, cent_bf, cc, count, sel, minmapped);

  k_final_out<<<128, 256, 0, stream>>>(feat, count, sel, minmapped, num, done, out);
}